// Round 1
// baseline (494.520 us; speedup 1.0000x reference)
//
#include <hip/hip_runtime.h>

// ---------------------------------------------------------------------------
// DefAddkeysTransformer on MI355X — round 0 baseline (pure fp32, no MFMA yet)
//
// Math notes (derived from the reference's reshape semantics):
//  * level attn rows: attn[h][l*4+a][b] = sum_d q[b][d] *
//        <W_attn[h*4+l][a*64 + (b>>4)], key[h,l,p=(b>>2)&3, qq=(b&3)*256+d]>
//    -> M-form: per (h,l,p,t): M = Q_sub(64x256) @ K_sub(256x256), then dot W rows.
//  * val projection: W_v @ (sum_r attn_r * key_r) + (sum_r attn_r) * b_v
// ---------------------------------------------------------------------------

// ---------------- generic tiled GEMM: C[m][n] = sum_k A[m][k]*B[n][k] -------
__global__ __launch_bounds__(256) void gemm_abt(
    const float* __restrict__ A, const float* __restrict__ B, float* __restrict__ C,
    int M, int N, int K, int sA, int sB, int sC, int ldC)
{
  __shared__ float As[16][65];
  __shared__ float Bs[16][65];
  const float* Ab = A + (size_t)blockIdx.z * sA;
  const float* Bb = B + (size_t)blockIdx.z * sB;
  float* Cb = C + (size_t)blockIdx.z * sC;
  int m0 = blockIdx.y * 64, n0 = blockIdx.x * 64;
  int t = threadIdx.x;
  int tm = t & 15, tn = t >> 4;
  int lr = t >> 4, lc = t & 15;
  float acc[4][4] = {};
  for (int k0 = 0; k0 < K; k0 += 16) {
    #pragma unroll
    for (int i = 0; i < 4; ++i) {
      int r = lr + i * 16;
      As[lc][r] = Ab[(m0 + r) * K + k0 + lc];
      Bs[lc][r] = Bb[(n0 + r) * K + k0 + lc];
    }
    __syncthreads();
    #pragma unroll
    for (int k = 0; k < 16; ++k) {
      float a[4], b[4];
      #pragma unroll
      for (int i = 0; i < 4; ++i) a[i] = As[k][tm * 4 + i];
      #pragma unroll
      for (int j = 0; j < 4; ++j) b[j] = Bs[k][tn * 4 + j];
      #pragma unroll
      for (int i = 0; i < 4; ++i)
        #pragma unroll
        for (int j = 0; j < 4; ++j) acc[i][j] += a[i] * b[j];
    }
    __syncthreads();
  }
  #pragma unroll
  for (int i = 0; i < 4; ++i)
    #pragma unroll
    for (int j = 0; j < 4; ++j)
      Cb[(m0 + tm * 4 + i) * ldC + n0 + tn * 4 + j] = acc[i][j];
}

// -------------- generic tiled GEMM: C[m][n] = sum_k A[k][m]*B[k][n] ---------
__global__ __launch_bounds__(256) void gemm_atb(
    const float* __restrict__ A, const float* __restrict__ B, float* __restrict__ C,
    int M, int N, int K, int ldA, int ldB, int sA, int sB, int sC, int ldC)
{
  __shared__ float As[16][65];
  __shared__ float Bs[16][65];
  const float* Ab = A + (size_t)blockIdx.z * sA;
  const float* Bb = B + (size_t)blockIdx.z * sB;
  float* Cb = C + (size_t)blockIdx.z * sC;
  int m0 = blockIdx.y * 64, n0 = blockIdx.x * 64;
  int t = threadIdx.x;
  int tm = t & 15, tn = t >> 4;
  int m = t & 63, kk = t >> 6;
  float acc[4][4] = {};
  for (int k0 = 0; k0 < K; k0 += 16) {
    #pragma unroll
    for (int i = 0; i < 4; ++i) {
      int k = kk + i * 4;
      As[k][m] = Ab[(k0 + k) * ldA + m0 + m];
      Bs[k][m] = Bb[(k0 + k) * ldB + n0 + m];
    }
    __syncthreads();
    #pragma unroll
    for (int k = 0; k < 16; ++k) {
      float a[4], b[4];
      #pragma unroll
      for (int i = 0; i < 4; ++i) a[i] = As[k][tm * 4 + i];
      #pragma unroll
      for (int j = 0; j < 4; ++j) b[j] = Bs[k][tn * 4 + j];
      #pragma unroll
      for (int i = 0; i < 4; ++i)
        #pragma unroll
        for (int j = 0; j < 4; ++j) acc[i][j] += a[i] * b[j];
    }
    __syncthreads();
  }
  #pragma unroll
  for (int i = 0; i < 4; ++i)
    #pragma unroll
    for (int j = 0; j < 4; ++j)
      Cb[(m0 + tm * 4 + i) * ldC + n0 + tn * 4 + j] = acc[i][j];
}

// ---------------- sampling locations -> flat gather indices -----------------
__global__ __launch_bounds__(128) void k_indices(
    const float* __restrict__ off_buf, const float* __restrict__ boff,
    const float* __restrict__ refpts, const int* __restrict__ shapes,
    const int* __restrict__ lvlst, int* __restrict__ fidx)
{
  int b = blockIdx.x, t = threadIdx.x;       // t = h*16 + l*4 + p
  int l = (t >> 2) & 3;
  float off0 = off_buf[b * 256 + 2 * t]     + boff[2 * t];
  float off1 = off_buf[b * 256 + 2 * t + 1] + boff[2 * t + 1];
  int Hi = shapes[2 * l], Wi = shapes[2 * l + 1];
  float Hf = (float)Hi, Wf = (float)Wi;
  float r0 = refpts[b * 8 + 2 * l], r1 = refpts[b * 8 + 2 * l + 1];
  // wh[l] = (W, H): x divided by W, y by H
  float l0 = fminf(fmaxf(r0 + off0 / Wf, 0.f), 0.999f);
  float l1 = fminf(fmaxf(r1 + off1 / Hf, 0.f), 0.999f);
  int i0 = (int)(l0 * Hf);
  int i1 = (int)(l1 * Wf);
  fidx[b * 128 + t] = i0 + i1 * Hi + lvlst[l];
}

// ------------- fused M-form level attention (rows 0..15 of attn) ------------
// block = (h, l, p, t_g); 256 threads; thread (tu=t>>4, tc=t&15) owns
// M[u=tu*4+i][c'=tc*16+j] for the 64 queries b = u*16 + p*4 + t_g.
__global__ __launch_bounds__(256) void k_attn_lvl(
    const float* __restrict__ q, const float* __restrict__ xin,
    const float* __restrict__ Wattn, const int* __restrict__ fidx,
    float* __restrict__ attn)
{
  __shared__ __align__(16) float Ks[32 * 260];  // [d_in_tile][c'] stride 260
  __shared__ float Qt[64 * 36];                 // [u][d_in_tile] stride 36
  __shared__ int fis[256];
  int h = blockIdx.z, l = blockIdx.y;
  int p = blockIdx.x >> 2, tg = blockIdx.x & 3;
  int t = threadIdx.x;
  int tu = t >> 4, tc = t & 15;
  fis[t] = fidx[(tg * 256 + t) * 128 + h * 16 + l * 4 + p];
  int qcol = p * 4 + tg;
  float acc[4][16];
  #pragma unroll
  for (int i = 0; i < 4; ++i)
    #pragma unroll
    for (int j = 0; j < 16; ++j) acc[i][j] = 0.f;

  for (int tile = 0; tile < 8; ++tile) {
    __syncthreads();
    #pragma unroll 8
    for (int rr = 0; rr < 32; ++rr)
      Ks[rr * 260 + t] = xin[fis[tile * 32 + rr] * 256 + t];
    {
      int u0 = t >> 5, dd = t & 31;
      #pragma unroll
      for (int kq = 0; kq < 8; ++kq) {
        int u = u0 + kq * 8;
        Qt[u * 36 + dd] = q[(u * 16 + qcol) * 256 + tile * 32 + dd];
      }
    }
    __syncthreads();
    #pragma unroll 2
    for (int rr = 0; rr < 32; ++rr) {
      float qa[4];
      #pragma unroll
      for (int i = 0; i < 4; ++i) qa[i] = Qt[(tu * 4 + i) * 36 + rr];
      const float4* kp = (const float4*)&Ks[rr * 260 + tc * 16];
      float4 k0 = kp[0], k1 = kp[1], k2 = kp[2], k3 = kp[3];
      float kv[16] = {k0.x, k0.y, k0.z, k0.w, k1.x, k1.y, k1.z, k1.w,
                      k2.x, k2.y, k2.z, k2.w, k3.x, k3.y, k3.z, k3.w};
      #pragma unroll
      for (int i = 0; i < 4; ++i)
        #pragma unroll
        for (int j = 0; j < 16; ++j) acc[i][j] += qa[i] * kv[j];
    }
  }
  // epilogue: attn[a][b] = <W_row[a*64+u], M[b]> via partials + 16-lane butterfly
  const float* Wb = Wattn + (h * 4 + l) * 65536;
  float outv[16];
  #pragma unroll
  for (int a = 0; a < 4; ++a) {
    #pragma unroll
    for (int i = 0; i < 4; ++i) {
      int u = tu * 4 + i;
      const float4* w4 = (const float4*)(Wb + (a * 64 + u) * 256 + tc * 16);
      float4 w0 = w4[0], w1 = w4[1], w2 = w4[2], w3 = w4[3];
      float s = w0.x * acc[i][0] + w0.y * acc[i][1] + w0.z * acc[i][2] + w0.w * acc[i][3]
              + w1.x * acc[i][4] + w1.y * acc[i][5] + w1.z * acc[i][6] + w1.w * acc[i][7]
              + w2.x * acc[i][8] + w2.y * acc[i][9] + w2.z * acc[i][10] + w2.w * acc[i][11]
              + w3.x * acc[i][12] + w3.y * acc[i][13] + w3.z * acc[i][14] + w3.w * acc[i][15];
      #pragma unroll
      for (int mm = 1; mm < 16; mm <<= 1) s += __shfl_xor(s, mm, 64);
      outv[a * 4 + i] = s;
    }
  }
  if (tc == 0) {
    #pragma unroll
    for (int a = 0; a < 4; ++a)
      #pragma unroll
      for (int i = 0; i < 4; ++i) {
        int u = tu * 4 + i;
        attn[(h * 272 + l * 4 + a) * 1024 + u * 16 + qcol] = outv[a * 4 + i];
      }
  }
}

// ------------------- softmax over 272 rows per (h, b) column ----------------
__global__ __launch_bounds__(128) void k_softmax(float* __restrict__ attn,
    float* __restrict__ s1, float* __restrict__ s2)
{
  int h = blockIdx.y;
  int b = blockIdx.x * 128 + threadIdx.x;
  float* col = attn + h * 278528 + b;
  float m = -1e30f;
  #pragma unroll 8
  for (int r = 0; r < 272; ++r) m = fmaxf(m, col[r * 1024]);
  float tot = 0.f, sa = 0.f;
  #pragma unroll 8
  for (int r = 0; r < 272; ++r) {
    float e = expf(col[r * 1024] - m);
    col[r * 1024] = e;
    tot += e;
    if (r < 16) sa += e;
  }
  float inv = 1.f / tot;
  #pragma unroll 8
  for (int r = 0; r < 272; ++r) col[r * 1024] *= inv;
  s1[h * 1024 + b] = sa * inv;
  s2[h * 1024 + b] = (tot - sa) * inv;
}

// --------------- kbar[h][b] = sum_{r<16} attn[h][r][b] * key_{h,r,b} --------
__global__ __launch_bounds__(256) void k_kbar(
    const float* __restrict__ xin, const float* __restrict__ attn,
    const int* __restrict__ fidx, float* __restrict__ kbar)
{
  __shared__ float aw[16 * 64];
  __shared__ int fis[64 * 16];
  int h = blockIdx.y, b0 = blockIdx.x * 64;
  int t = threadIdx.x;
  #pragma unroll
  for (int i = 0; i < 4; ++i) {
    int idx = i * 256 + t;
    int r = idx >> 6, bi = idx & 63;
    aw[r * 64 + bi] = attn[(h * 272 + r) * 1024 + b0 + bi];
    int bi2 = idx >> 4, r2 = idx & 15;
    fis[idx] = fidx[(b0 + bi2) * 128 + h * 16 + r2];
  }
  __syncthreads();
  for (int bi = 0; bi < 64; ++bi) {
    float s = 0.f;
    #pragma unroll
    for (int r = 0; r < 16; ++r)
      s += aw[r * 64 + bi] * xin[fis[bi * 16 + r] * 256 + t];
    kbar[(h * 1024 + b0 + bi) * 256 + t] = s;
  }
}

// ------------------------------- final combine ------------------------------
__global__ __launch_bounds__(256) void k_combine(
    const float* __restrict__ q, const float* __restrict__ Wmix,
    const float* __restrict__ Y1, const float* __restrict__ Y2,
    const float* __restrict__ s1, const float* __restrict__ s2,
    const float* __restrict__ bval, float* __restrict__ out)
{
  int b = blockIdx.x, c = threadIdx.x;
  float w[9];
  float m = -1e30f;
  #pragma unroll
  for (int j = 0; j < 9; ++j) { w[j] = Wmix[c * 9 + j]; m = fmaxf(m, w[j]); }
  float tot = 0.f;
  #pragma unroll
  for (int j = 0; j < 9; ++j) { w[j] = expf(w[j] - m); tot += w[j]; }
  float inv = 1.f / tot;
  float res = q[b * 256 + c] * w[8] * inv;
  #pragma unroll
  for (int hh = 0; hh < 8; ++hh) {
    float y = Y1[(hh * 1024 + b) * 256 + c] + Y2[(hh * 1024 + b) * 256 + c]
            + s1[hh * 1024 + b] * bval[(2 * hh) * 256 + c]
            + s2[hh * 1024 + b] * bval[(2 * hh + 1) * 256 + c];
    res += w[hh] * inv * y;
  }
  out[b * 256 + c] = res;
}

extern "C" void kernel_launch(void* const* d_in, const int* in_sizes, int n_in,
                              void* d_out, int out_size, void* d_ws, size_t ws_size,
                              hipStream_t stream) {
  (void)in_sizes; (void)n_in; (void)out_size; (void)ws_size;
  const float* q      = (const float*)d_in[0];
  const float* refpts = (const float*)d_in[1];
  const float* xin    = (const float*)d_in[2];
  const int*   shapes = (const int*)d_in[3];
  const float* addk   = (const float*)d_in[4];
  const int*   lvlst  = (const int*)d_in[5];
  const float* Woff   = (const float*)d_in[6];
  const float* boff   = (const float*)d_in[7];
  const float* Wattn  = (const float*)d_in[8];
  const float* Wval   = (const float*)d_in[9];
  const float* bval   = (const float*)d_in[10];
  const float* Wmix   = (const float*)d_in[11];
  float* out = (float*)d_out;
  float* ws  = (float*)d_ws;

  float* off_buf = ws;                        // 262144 f
  int*   fidx    = (int*)(ws + 262144);       // 131072 i
  float* attn    = ws + 393216;               // 8*272*1024
  float* tmp     = ws + 2621440;              // 8*256*256
  float* kbar    = ws + 3145728;              // 8*1024*256
  float* abar    = ws + 5242880;              // 8*1024*256
  float* Y1      = ws + 7340032;              // 8*1024*256
  float* Y2      = ws + 9437184;              // 8*1024*256
  float* s1      = ws + 11534336;             // 8*1024
  float* s2      = ws + 11542528;             // 8*1024

  // 1. off = q @ W_off^T   (bias added in k_indices)
  gemm_abt<<<dim3(4, 16, 1), 256, 0, stream>>>(q, Woff, off_buf, 1024, 256, 256, 0, 0, 0, 256);
  // 2. gather indices
  k_indices<<<1024, 128, 0, stream>>>(off_buf, boff, refpts, shapes, lvlst, fidx);
  // 3. level attention logits (attn rows 0..15)
  k_attn_lvl<<<dim3(16, 4, 8), 256, 0, stream>>>(q, xin, Wattn, fidx, attn);
  // 4. tmp[h] = addk @ W_attn[h*4+4]^T
  gemm_abt<<<dim3(4, 4, 8), 256, 0, stream>>>(addk, Wattn + 4 * 65536, tmp,
                                              256, 256, 256, 0, 262144, 65536, 256);
  // 5. attn rows 16..271: tmp[h] @ q^T
  gemm_abt<<<dim3(16, 4, 8), 256, 0, stream>>>(tmp, q, attn + 16384,
                                               256, 1024, 256, 65536, 0, 278528, 1024);
  // 6. softmax over the 272 rows (+ s1/s2 bias sums)
  k_softmax<<<dim3(8, 8), 128, 0, stream>>>(attn, s1, s2);
  // 7. kbar gather-reduce
  k_kbar<<<dim3(16, 8), 256, 0, stream>>>(xin, attn, fidx, kbar);
  // 8. abar[h] = attn2[h]^T @ addk
  gemm_atb<<<dim3(4, 16, 8), 256, 0, stream>>>(attn + 16384, addk, abar,
                                               1024, 256, 256, 1024, 256, 278528, 0, 262144, 256);
  // 9. Y1[h] = kbar[h] @ W_val[2h]^T ; Y2[h] = abar[h] @ W_val[2h+1]^T
  gemm_abt<<<dim3(4, 16, 8), 256, 0, stream>>>(kbar, Wval, Y1,
                                               1024, 256, 256, 262144, 131072, 262144, 256);
  gemm_abt<<<dim3(4, 16, 8), 256, 0, stream>>>(abar, Wval + 65536, Y2,
                                               1024, 256, 256, 262144, 131072, 262144, 256);
  // 10. combine with head softmax + biases
  k_combine<<<1024, 256, 0, stream>>>(q, Wmix, Y1, Y2, s1, s2, bval, out);
}

// Round 2
// 307.775 us; speedup vs baseline: 1.6068x; 1.6068x over previous
//
#include <hip/hip_runtime.h>

typedef unsigned short ushort_t;
typedef __attribute__((ext_vector_type(8))) short bh8;     // 8 bf16 (4 VGPRs)
typedef __attribute__((ext_vector_type(4))) float f4;      // 4 fp32 acc
typedef __attribute__((ext_vector_type(4))) unsigned int u4;

__device__ __forceinline__ ushort_t f2bf(float f) {
  unsigned u = __float_as_uint(f);
  return (ushort_t)((u + 0x7FFFu + ((u >> 16) & 1u)) >> 16);
}
__device__ __forceinline__ float bf2f(ushort_t v) {
  return __uint_as_float(((unsigned)v) << 16);
}

// ---------------------------------------------------------------------------
// cast q / xin / addk / Wval / Wattn-add-mats to bf16 arena (4-wide)
// arena ushort offsets: q:0  xin:262144  addk:3665408  Wval:3730944  Wattn4:4779520
// ---------------------------------------------------------------------------
__global__ __launch_bounds__(256) void k_cast(
    const float* __restrict__ q, const float* __restrict__ xin,
    const float* __restrict__ addk, const float* __restrict__ Wval,
    const float* __restrict__ Wattn, ushort_t* __restrict__ arena)
{
  const int total4 = 1325952;
  for (int i = blockIdx.x * 256 + threadIdx.x; i < total4; i += gridDim.x * 256) {
    const float* src; ushort_t* dst; int e;
    if (i < 65536)        { src = q    + i * 4;            dst = arena + i * 4; }
    else if (i < 916352)  { e = i - 65536;  src = xin  + e * 4; dst = arena + 262144  + e * 4; }
    else if (i < 932736)  { e = i - 916352; src = addk + e * 4; dst = arena + 3665408 + e * 4; }
    else if (i < 1194880) { e = i - 932736; src = Wval + e * 4; dst = arena + 3730944 + e * 4; }
    else { e = i - 1194880; int h = (e * 4) >> 16; int off = (e * 4) & 65535;
           src = Wattn + h * 262144 + 262144 + off; dst = arena + 4779520 + e * 4; }
    float4 v = *(const float4*)src;
    ushort4 o; o.x = f2bf(v.x); o.y = f2bf(v.y); o.z = f2bf(v.z); o.w = f2bf(v.w);
    *(ushort4*)dst = o;
  }
}

// ------------- fp32 tiled GEMM (kept for the offset projection only) --------
__global__ __launch_bounds__(256) void gemm_f32(
    const float* __restrict__ A, const float* __restrict__ B, float* __restrict__ C,
    int M, int N, int K, int ldC)
{
  __shared__ float As[16][65];
  __shared__ float Bs[16][65];
  int m0 = blockIdx.y * 64, n0 = blockIdx.x * 64;
  int t = threadIdx.x;
  int tm = t & 15, tn = t >> 4;
  int lr = t >> 4, lc = t & 15;
  float acc[4][4] = {};
  for (int k0 = 0; k0 < K; k0 += 16) {
    #pragma unroll
    for (int i = 0; i < 4; ++i) {
      int r = lr + i * 16;
      As[lc][r] = A[(m0 + r) * K + k0 + lc];
      Bs[lc][r] = B[(n0 + r) * K + k0 + lc];
    }
    __syncthreads();
    #pragma unroll
    for (int k = 0; k < 16; ++k) {
      float a[4], b[4];
      #pragma unroll
      for (int i = 0; i < 4; ++i) a[i] = As[k][tm * 4 + i];
      #pragma unroll
      for (int j = 0; j < 4; ++j) b[j] = Bs[k][tn * 4 + j];
      #pragma unroll
      for (int i = 0; i < 4; ++i)
        #pragma unroll
        for (int j = 0; j < 4; ++j) acc[i][j] += a[i] * b[j];
    }
    __syncthreads();
  }
  #pragma unroll
  for (int i = 0; i < 4; ++i)
    #pragma unroll
    for (int j = 0; j < 4; ++j)
      C[(m0 + tm * 4 + i) * ldC + n0 + tn * 4 + j] = acc[i][j];
}

// ---------------- sampling locations -> flat gather indices -----------------
__global__ __launch_bounds__(128) void k_indices(
    const float* __restrict__ off_buf, const float* __restrict__ boff,
    const float* __restrict__ refpts, const int* __restrict__ shapes,
    const int* __restrict__ lvlst, int* __restrict__ fidx)
{
  int b = blockIdx.x, t = threadIdx.x;       // t = h*16 + l*4 + p
  int l = (t >> 2) & 3;
  float off0 = off_buf[b * 256 + 2 * t]     + boff[2 * t];
  float off1 = off_buf[b * 256 + 2 * t + 1] + boff[2 * t + 1];
  int Hi = shapes[2 * l], Wi = shapes[2 * l + 1];
  float Hf = (float)Hi, Wf = (float)Wi;
  float r0 = refpts[b * 8 + 2 * l], r1 = refpts[b * 8 + 2 * l + 1];
  float l0 = fminf(fmaxf(r0 + off0 / Wf, 0.f), 0.999f);
  float l1 = fminf(fmaxf(r1 + off1 / Hf, 0.f), 0.999f);
  int i0 = (int)(l0 * Hf);
  int i1 = (int)(l1 * Wf);
  fidx[b * 128 + t] = i0 + i1 * Hi + lvlst[l];
}

// ---------------------------------------------------------------------------
// MFMA level-attention: per block (h,l,p,tg):
//   N[u][c'] = sum_j q_bf[b(u)][j] * xin_bf[fis[j]][c']   (64x256x256 GEMM)
//   attn[l*4+a][b(u)] = sum_c' W[(h*4+l)][a*64+u][c'] * N[u][c']  (fp32 epilogue)
// b(u) = u*16 + p*4 + tg.  Gathered keys transposed into LDS (pair-packed).
// ---------------------------------------------------------------------------
__global__ __launch_bounds__(256) void k_attn_mfma(
    const ushort_t* __restrict__ qbf, const ushort_t* __restrict__ xbf,
    const float* __restrict__ Wattn, const int* __restrict__ fidx,
    float* __restrict__ attn)
{
  __shared__ __align__(16) unsigned Bs[256 * 34];   // [c'][j-pair] stride 34 words
  __shared__ __align__(16) ushort_t As[64 * 72];    // [u][j] stride 72 (144 B)
  __shared__ int fis[256];
  __shared__ float red[256 * 4];
  int h = blockIdx.z, l = blockIdx.y;
  int p = blockIdx.x >> 2, tg = blockIdx.x & 3;
  int t = threadIdx.x;
  int lane = t & 63, w = t >> 6;
  int quad = lane >> 4, l15 = lane & 15;
  int qcol = p * 4 + tg;
  fis[t] = fidx[(tg * 256 + t) * 128 + h * 16 + l * 4 + p];
  __syncthreads();
  f4 acc[4][4];
  #pragma unroll
  for (int mi = 0; mi < 4; ++mi)
    #pragma unroll
    for (int ni = 0; ni < 4; ++ni) acc[mi][ni] = (f4)0.f;

  for (int jt = 0; jt < 4; ++jt) {
    if (jt) __syncthreads();
    // stage B transposed: thread t = channel c'
    #pragma unroll 4
    for (int jq = 0; jq < 16; ++jq) {
      int j0 = jt * 64 + jq * 4;
      unsigned a0 = xbf[fis[j0 + 0] * 256 + t];
      unsigned a1 = xbf[fis[j0 + 1] * 256 + t];
      unsigned a2 = xbf[fis[j0 + 2] * 256 + t];
      unsigned a3 = xbf[fis[j0 + 3] * 256 + t];
      uint2 v; v.x = a0 | (a1 << 16); v.y = a2 | (a3 << 16);
      *(uint2*)&Bs[t * 34 + jq * 2] = v;
    }
    // stage A (Q rows)
    {
      int u = t >> 2, jj0 = (t & 3) * 16;
      const u4* src = (const u4*)(qbf + (u * 16 + qcol) * 256 + jt * 64 + jj0);
      u4 s0 = src[0], s1 = src[1];
      u4* dst = (u4*)(As + u * 72 + jj0);
      dst[0] = s0; dst[1] = s1;
    }
    __syncthreads();
    #pragma unroll
    for (int ks = 0; ks < 2; ++ks) {
      bh8 af[4], bfv[4];
      #pragma unroll
      for (int mi = 0; mi < 4; ++mi)
        af[mi] = *(bh8*)(As + (mi * 16 + l15) * 72 + ks * 32 + quad * 8);
      #pragma unroll
      for (int ni = 0; ni < 4; ++ni) {
        int n = w * 64 + ni * 16 + l15;
        const unsigned* bp = &Bs[n * 34 + ks * 16 + quad * 4];
        uint2 b0 = *(const uint2*)bp;
        uint2 b1 = *(const uint2*)(bp + 2);
        u4 bb; bb.x = b0.x; bb.y = b0.y; bb.z = b1.x; bb.w = b1.y;
        bfv[ni] = __builtin_bit_cast(bh8, bb);
      }
      #pragma unroll
      for (int mi = 0; mi < 4; ++mi)
        #pragma unroll
        for (int ni = 0; ni < 4; ++ni)
          acc[mi][ni] = __builtin_amdgcn_mfma_f32_16x16x32_bf16(af[mi], bfv[ni], acc[mi][ni], 0, 0, 0);
    }
  }
  // fp32 epilogue: dot N rows with W rows, reduce over c'
  const float* Wb = Wattn + (h * 4 + l) * 65536;
  #pragma unroll
  for (int a = 0; a < 4; ++a) {
    #pragma unroll
    for (int mi = 0; mi < 4; ++mi) {
      #pragma unroll
      for (int r = 0; r < 4; ++r) {
        int u = mi * 16 + quad * 4 + r;
        const float* wr = Wb + (a * 64 + u) * 256 + w * 64 + l15;
        float s = acc[mi][0][r] * wr[0]  + acc[mi][1][r] * wr[16]
                + acc[mi][2][r] * wr[32] + acc[mi][3][r] * wr[48];
        s += __shfl_xor(s, 1, 64); s += __shfl_xor(s, 2, 64);
        s += __shfl_xor(s, 4, 64); s += __shfl_xor(s, 8, 64);
        if (l15 == 0) red[(a * 64 + u) * 4 + w] = s;
      }
    }
  }
  __syncthreads();
  {
    int a = t >> 6, u = t & 63;
    float s = red[t * 4 + 0] + red[t * 4 + 1] + red[t * 4 + 2] + red[t * 4 + 3];
    attn[(h * 272 + l * 4 + a) * 1024 + u * 16 + qcol] = s;
  }
}

// ---------------------------------------------------------------------------
// bf16 MFMA GEMM core, abt form: C[m][n] = sum_k A[m][k]*B[n][k]
// ldA=ldB=256, K=256 hardcoded. 128x128 tile, 4 waves of 64x64.
// ---------------------------------------------------------------------------
template <typename OutT>
__device__ __forceinline__ void gemm_abt_core(
    const ushort_t* __restrict__ A, const ushort_t* __restrict__ B,
    OutT* __restrict__ C, int ldC, int m0, int n0)
{
  __shared__ __align__(16) ushort_t As[128 * 40];
  __shared__ __align__(16) ushort_t Bs[128 * 40];
  int t = threadIdx.x;
  int lane = t & 63, w = t >> 6;
  int quad = lane >> 4, l15 = lane & 15;
  int wm = w >> 1, wn = w & 1;
  f4 acc[4][4];
  #pragma unroll
  for (int mi = 0; mi < 4; ++mi)
    #pragma unroll
    for (int ni = 0; ni < 4; ++ni) acc[mi][ni] = (f4)0.f;
  int row = t >> 1, kh = (t & 1) * 16;
  for (int k0 = 0; k0 < 256; k0 += 32) {
    if (k0) __syncthreads();
    {
      const u4* ga = (const u4*)(A + (m0 + row) * 256 + k0 + kh);
      u4 v0 = ga[0], v1 = ga[1];
      u4* da = (u4*)(As + row * 40 + kh); da[0] = v0; da[1] = v1;
      const u4* gb = (const u4*)(B + (n0 + row) * 256 + k0 + kh);
      u4 u0 = gb[0], u1 = gb[1];
      u4* db = (u4*)(Bs + row * 40 + kh); db[0] = u0; db[1] = u1;
    }
    __syncthreads();
    bh8 af[4], bfv[4];
    #pragma unroll
    for (int mi = 0; mi < 4; ++mi)
      af[mi] = *(bh8*)(As + (wm * 64 + mi * 16 + l15) * 40 + quad * 8);
    #pragma unroll
    for (int ni = 0; ni < 4; ++ni)
      bfv[ni] = *(bh8*)(Bs + (wn * 64 + ni * 16 + l15) * 40 + quad * 8);
    #pragma unroll
    for (int mi = 0; mi < 4; ++mi)
      #pragma unroll
      for (int ni = 0; ni < 4; ++ni)
        acc[mi][ni] = __builtin_amdgcn_mfma_f32_16x16x32_bf16(af[mi], bfv[ni], acc[mi][ni], 0, 0, 0);
  }
  #pragma unroll
  for (int mi = 0; mi < 4; ++mi)
    #pragma unroll
    for (int ni = 0; ni < 4; ++ni)
      #pragma unroll
      for (int r = 0; r < 4; ++r) {
        int mg = m0 + wm * 64 + mi * 16 + quad * 4 + r;
        int ng = n0 + wn * 64 + ni * 16 + l15;
        if constexpr (sizeof(OutT) == 4) C[mg * ldC + ng] = acc[mi][ni][r];
        else C[mg * ldC + ng] = (OutT)f2bf(acc[mi][ni][r]);
      }
}

// step 4: tmp[h] = addk_bf @ Wattn4_bf[h]^T  (bf16 out)
__global__ __launch_bounds__(256) void gemm4_k(
    const ushort_t* __restrict__ addk, const ushort_t* __restrict__ Wattn4,
    ushort_t* __restrict__ tmp)
{
  int h = blockIdx.z;
  gemm_abt_core<ushort_t>(addk, Wattn4 + h * 65536, tmp + h * 65536,
                          256, blockIdx.y * 128, blockIdx.x * 128);
}
// step 5: attn rows 16..271 = tmp[h] @ q_bf^T  (fp32 out, ldC=1024)
__global__ __launch_bounds__(256) void gemm5_k(
    const ushort_t* __restrict__ tmp, const ushort_t* __restrict__ qbf,
    float* __restrict__ attn)
{
  int h = blockIdx.z;
  gemm_abt_core<float>(tmp + h * 65536, qbf, attn + h * 278528 + 16384,
                       1024, blockIdx.y * 128, blockIdx.x * 128);
}
// step 9: Y1 = kbar_bf @ Wval[2h]^T ; Y2 = abar_bf @ Wval[2h+1]^T  (fp32 out)
__global__ __launch_bounds__(256) void gemm_val_k(
    const ushort_t* __restrict__ kbar, const ushort_t* __restrict__ abar,
    const ushort_t* __restrict__ Wval, float* __restrict__ Y1, float* __restrict__ Y2)
{
  int z = blockIdx.z, h = z & 7;
  const ushort_t* A = (z < 8 ? kbar : abar) + h * 262144;
  const ushort_t* B = Wval + (z < 8 ? 2 * h : 2 * h + 1) * 65536;
  float* C = (z < 8 ? Y1 : Y2) + h * 262144;
  gemm_abt_core<float>(A, B, C, 256, blockIdx.y * 128, blockIdx.x * 128);
}

// ---------------------------------------------------------------------------
// TN GEMM: abar[b][c] = sum_r attn2[r][b] * addk[r][c]  (both ops k-major)
// A ld=1024 (m-contig), B ld=256 (n-contig); transposed pair-packed staging.
// ---------------------------------------------------------------------------
__global__ __launch_bounds__(256) void gemm_tn_k(
    const ushort_t* __restrict__ attn2, const ushort_t* __restrict__ addk,
    ushort_t* __restrict__ abar)
{
  __shared__ __align__(16) unsigned Asu[128 * 20];
  __shared__ __align__(16) unsigned Bsu[128 * 20];
  int h = blockIdx.z;
  const ushort_t* A = attn2 + h * 262144;
  const ushort_t* B = addk;
  ushort_t* C = abar + h * 262144;
  int m0 = blockIdx.y * 128, n0 = blockIdx.x * 128;
  int t = threadIdx.x;
  int lane = t & 63, w = t >> 6;
  int quad = lane >> 4, l15 = lane & 15;
  int wm = w >> 1, wn = w & 1;
  f4 acc[4][4];
  #pragma unroll
  for (int mi = 0; mi < 4; ++mi)
    #pragma unroll
    for (int ni = 0; ni < 4; ++ni) acc[mi][ni] = (f4)0.f;
  int col = t & 127, half = t >> 7;
  for (int k0 = 0; k0 < 256; k0 += 32) {
    if (k0) __syncthreads();
    #pragma unroll
    for (int i = 0; i < 4; ++i) {
      int kpp = half * 4 + i;            // uint2 unit: covers k = 4*kpp .. 4*kpp+3
      int kk = k0 + kpp * 4;
      unsigned x0 = A[(kk + 0) * 1024 + m0 + col];
      unsigned x1 = A[(kk + 1) * 1024 + m0 + col];
      unsigned x2 = A[(kk + 2) * 1024 + m0 + col];
      unsigned x3 = A[(kk + 3) * 1024 + m0 + col];
      uint2 va; va.x = x0 | (x1 << 16); va.y = x2 | (x3 << 16);
      *(uint2*)&Asu[col * 20 + kpp * 2] = va;
      unsigned y0 = B[(kk + 0) * 256 + n0 + col];
      unsigned y1 = B[(kk + 1) * 256 + n0 + col];
      unsigned y2 = B[(kk + 2) * 256 + n0 + col];
      unsigned y3 = B[(kk + 3) * 256 + n0 + col];
      uint2 vb; vb.x = y0 | (y1 << 16); vb.y = y2 | (y3 << 16);
      *(uint2*)&Bsu[col * 20 + kpp * 2] = vb;
    }
    __syncthreads();
    bh8 af[4], bfv[4];
    #pragma unroll
    for (int mi = 0; mi < 4; ++mi)
      af[mi] = *(bh8*)((const ushort_t*)Asu + (wm * 64 + mi * 16 + l15) * 40 + quad * 8);
    #pragma unroll
    for (int ni = 0; ni < 4; ++ni)
      bfv[ni] = *(bh8*)((const ushort_t*)Bsu + (wn * 64 + ni * 16 + l15) * 40 + quad * 8);
    #pragma unroll
    for (int mi = 0; mi < 4; ++mi)
      #pragma unroll
      for (int ni = 0; ni < 4; ++ni)
        acc[mi][ni] = __builtin_amdgcn_mfma_f32_16x16x32_bf16(af[mi], bfv[ni], acc[mi][ni], 0, 0, 0);
  }
  #pragma unroll
  for (int mi = 0; mi < 4; ++mi)
    #pragma unroll
    for (int ni = 0; ni < 4; ++ni)
      #pragma unroll
      for (int r = 0; r < 4; ++r) {
        int mg = m0 + wm * 64 + mi * 16 + quad * 4 + r;
        int ng = n0 + wn * 64 + ni * 16 + l15;
        C[mg * 256 + ng] = f2bf(acc[mi][ni][r]);
      }
}

// ------------------- softmax over 272 rows per (h, b) column ----------------
__global__ __launch_bounds__(128) void k_softmax(float* __restrict__ attn,
    ushort_t* __restrict__ attn2bf, float* __restrict__ s1, float* __restrict__ s2)
{
  int h = blockIdx.y;
  int b = blockIdx.x * 128 + threadIdx.x;
  float* col = attn + h * 278528 + b;
  float m = -1e30f;
  #pragma unroll 8
  for (int r = 0; r < 272; ++r) m = fmaxf(m, col[r * 1024]);
  float tot = 0.f, sa = 0.f;
  #pragma unroll 8
  for (int r = 0; r < 272; ++r) {
    float e = expf(col[r * 1024] - m);
    col[r * 1024] = e;
    tot += e;
    if (r < 16) sa += e;
  }
  float inv = 1.f / tot;
  #pragma unroll 8
  for (int r = 0; r < 272; ++r) {
    float v = col[r * 1024] * inv;
    col[r * 1024] = v;
    if (r >= 16) attn2bf[h * 262144 + (r - 16) * 1024 + b] = f2bf(v);
  }
  s1[h * 1024 + b] = sa * inv;
  s2[h * 1024 + b] = (tot - sa) * inv;
}

// --------------- kbar[h][b] = sum_{r<16} attn[h][r][b] * key_{h,r,b} --------
__global__ __launch_bounds__(256) void k_kbar(
    const ushort_t* __restrict__ xbf, const float* __restrict__ attn,
    const int* __restrict__ fidx, ushort_t* __restrict__ kbar)
{
  __shared__ float aw[256];     // [r][bi]
  __shared__ int fis2[256];     // [bi][r]
  int h = blockIdx.y, b0 = blockIdx.x * 16;
  int t = threadIdx.x;
  aw[t] = attn[(h * 272 + (t >> 4)) * 1024 + b0 + (t & 15)];
  fis2[t] = fidx[(b0 + (t >> 4)) * 128 + h * 16 + (t & 15)];
  __syncthreads();
  #pragma unroll 2
  for (int bi = 0; bi < 16; ++bi) {
    float s = 0.f;
    #pragma unroll
    for (int r = 0; r < 16; ++r)
      s += aw[r * 16 + bi] * bf2f(xbf[fis2[bi * 16 + r] * 256 + t]);
    kbar[(h * 1024 + b0 + bi) * 256 + t] = f2bf(s);
  }
}

// ------------------------------- final combine ------------------------------
__global__ __launch_bounds__(256) void k_combine(
    const float* __restrict__ q, const float* __restrict__ Wmix,
    const float* __restrict__ Y1, const float* __restrict__ Y2,
    const float* __restrict__ s1, const float* __restrict__ s2,
    const float* __restrict__ bval, float* __restrict__ out)
{
  int b = blockIdx.x, c = threadIdx.x;
  float w[9];
  float m = -1e30f;
  #pragma unroll
  for (int j = 0; j < 9; ++j) { w[j] = Wmix[c * 9 + j]; m = fmaxf(m, w[j]); }
  float tot = 0.f;
  #pragma unroll
  for (int j = 0; j < 9; ++j) { w[j] = expf(w[j] - m); tot += w[j]; }
  float inv = 1.f / tot;
  float res = q[b * 256 + c] * w[8] * inv;
  #pragma unroll
  for (int hh = 0; hh < 8; ++hh) {
    float y = Y1[(hh * 1024 + b) * 256 + c] + Y2[(hh * 1024 + b) * 256 + c]
            + s1[hh * 1024 + b] * bval[(2 * hh) * 256 + c]
            + s2[hh * 1024 + b] * bval[(2 * hh + 1) * 256 + c];
    res += w[hh] * inv * y;
  }
  out[b * 256 + c] = res;
}

extern "C" void kernel_launch(void* const* d_in, const int* in_sizes, int n_in,
                              void* d_out, int out_size, void* d_ws, size_t ws_size,
                              hipStream_t stream) {
  (void)in_sizes; (void)n_in; (void)out_size; (void)ws_size;
  const float* q      = (const float*)d_in[0];
  const float* refpts = (const float*)d_in[1];
  const float* xin    = (const float*)d_in[2];
  const int*   shapes = (const int*)d_in[3];
  const float* addk   = (const float*)d_in[4];
  const int*   lvlst  = (const int*)d_in[5];
  const float* Woff   = (const float*)d_in[6];
  const float* boff   = (const float*)d_in[7];
  const float* Wattn  = (const float*)d_in[8];
  const float* Wval   = (const float*)d_in[9];
  const float* bval   = (const float*)d_in[10];
  const float* Wmix   = (const float*)d_in[11];
  float* out = (float*)d_out;
  float* ws  = (float*)d_ws;

  int*   fidx    = (int*)ws;                  // [0, 131072)
  float* off_buf = ws + 131072;               // 262144 f
  float* s1      = ws + 393216;               // 8192
  float* s2      = ws + 401408;               // 8192
  float* attn    = ws + 409600;               // 8*272*1024 fp32 (dead after k_kbar)
  float* Y1      = ws + 409600;               // overlaps attn (written by gemm_val_k)
  float* Y2      = ws + 2506752;              // 8*1024*256
  ushort_t* arena = (ushort_t*)(ws + 4603904);
  ushort_t* q_bf     = arena;                 // 262144
  ushort_t* xin_bf   = arena + 262144;        // 3403264
  ushort_t* addk_bf  = arena + 3665408;       // 65536
  ushort_t* Wval_bf  = arena + 3730944;       // 1048576
  ushort_t* Wattn4_bf= arena + 4779520;       // 524288
  ushort_t* tmp_bf   = arena + 5303808;       // 524288
  ushort_t* attn2_bf = arena + 5828096;       // 2097152
  ushort_t* kbar_bf  = arena + 7925248;       // 2097152
  ushort_t* abar_bf  = arena + 10022400;      // 2097152

  k_cast<<<2048, 256, 0, stream>>>(q, xin, addk, Wval, Wattn, arena);
  gemm_f32<<<dim3(4, 16, 1), 256, 0, stream>>>(q, Woff, off_buf, 1024, 256, 256, 256);
  k_indices<<<1024, 128, 0, stream>>>(off_buf, boff, refpts, shapes, lvlst, fidx);
  k_attn_mfma<<<dim3(16, 4, 8), 256, 0, stream>>>(q_bf, xin_bf, Wattn, fidx, attn);
  gemm4_k<<<dim3(2, 2, 8), 256, 0, stream>>>(addk_bf, Wattn4_bf, tmp_bf);
  gemm5_k<<<dim3(8, 2, 8), 256, 0, stream>>>(tmp_bf, q_bf, attn);
  k_softmax<<<dim3(8, 8), 128, 0, stream>>>(attn, attn2_bf, s1, s2);
  k_kbar<<<dim3(64, 8), 256, 0, stream>>>(xin_bf, attn, fidx, kbar_bf);
  gemm_tn_k<<<dim3(2, 8, 8), 256, 0, stream>>>(attn2_bf, addk_bf, abar_bf);
  gemm_val_k<<<dim3(2, 8, 16), 256, 0, stream>>>(kbar_bf, abar_bf, Wval_bf, Y1, Y2);
  k_combine<<<1024, 256, 0, stream>>>(q, Wmix, Y1, Y2, s1, s2, bval, out);
}

// Round 3
// 232.252 us; speedup vs baseline: 2.1292x; 1.3252x over previous
//
#include <hip/hip_runtime.h>

typedef unsigned short ushort_t;
typedef __attribute__((ext_vector_type(8))) short bh8;     // 8 bf16 (4 VGPRs)
typedef __attribute__((ext_vector_type(4))) float f4;      // 4 fp32 acc
typedef __attribute__((ext_vector_type(4))) unsigned int u4;

__device__ __forceinline__ ushort_t f2bf(float f) {
  unsigned u = __float_as_uint(f);
  return (ushort_t)((u + 0x7FFFu + ((u >> 16) & 1u)) >> 16);
}
__device__ __forceinline__ float bf2f(ushort_t v) {
  return __uint_as_float(((unsigned)v) << 16);
}

// ---------------------------------------------------------------------------
// cast q / xin / addk / Wval / Wattn-add-mats to bf16 arena (4-wide)
// ---------------------------------------------------------------------------
__global__ __launch_bounds__(256) void k_cast(
    const float* __restrict__ q, const float* __restrict__ xin,
    const float* __restrict__ addk, const float* __restrict__ Wval,
    const float* __restrict__ Wattn, ushort_t* __restrict__ arena)
{
  const int total4 = 1325952;
  for (int i = blockIdx.x * 256 + threadIdx.x; i < total4; i += gridDim.x * 256) {
    const float* src; ushort_t* dst; int e;
    if (i < 65536)        { src = q    + i * 4;            dst = arena + i * 4; }
    else if (i < 916352)  { e = i - 65536;  src = xin  + e * 4; dst = arena + 262144  + e * 4; }
    else if (i < 932736)  { e = i - 916352; src = addk + e * 4; dst = arena + 3665408 + e * 4; }
    else if (i < 1194880) { e = i - 932736; src = Wval + e * 4; dst = arena + 3730944 + e * 4; }
    else { e = i - 1194880; int h = (e * 4) >> 16; int off = (e * 4) & 65535;
           src = Wattn + h * 262144 + 262144 + off; dst = arena + 4779520 + e * 4; }
    float4 v = *(const float4*)src;
    ushort4 o; o.x = f2bf(v.x); o.y = f2bf(v.y); o.z = f2bf(v.z); o.w = f2bf(v.w);
    *(ushort4*)dst = o;
  }
}

// ------------- fp32 tiled GEMM (kept for the offset projection only) --------
__global__ __launch_bounds__(256) void gemm_f32(
    const float* __restrict__ A, const float* __restrict__ B, float* __restrict__ C,
    int M, int N, int K, int ldC)
{
  __shared__ float As[16][65];
  __shared__ float Bs[16][65];
  int m0 = blockIdx.y * 64, n0 = blockIdx.x * 64;
  int t = threadIdx.x;
  int tm = t & 15, tn = t >> 4;
  int lr = t >> 4, lc = t & 15;
  float acc[4][4] = {};
  for (int k0 = 0; k0 < K; k0 += 16) {
    #pragma unroll
    for (int i = 0; i < 4; ++i) {
      int r = lr + i * 16;
      As[lc][r] = A[(m0 + r) * K + k0 + lc];
      Bs[lc][r] = B[(n0 + r) * K + k0 + lc];
    }
    __syncthreads();
    #pragma unroll
    for (int k = 0; k < 16; ++k) {
      float a[4], b[4];
      #pragma unroll
      for (int i = 0; i < 4; ++i) a[i] = As[k][tm * 4 + i];
      #pragma unroll
      for (int j = 0; j < 4; ++j) b[j] = Bs[k][tn * 4 + j];
      #pragma unroll
      for (int i = 0; i < 4; ++i)
        #pragma unroll
        for (int j = 0; j < 4; ++j) acc[i][j] += a[i] * b[j];
    }
    __syncthreads();
  }
  #pragma unroll
  for (int i = 0; i < 4; ++i)
    #pragma unroll
    for (int j = 0; j < 4; ++j)
      C[(m0 + tm * 4 + i) * ldC + n0 + tn * 4 + j] = acc[i][j];
}

// ---------------- sampling locations -> flat gather indices -----------------
__global__ __launch_bounds__(128) void k_indices(
    const float* __restrict__ off_buf, const float* __restrict__ boff,
    const float* __restrict__ refpts, const int* __restrict__ shapes,
    const int* __restrict__ lvlst, int* __restrict__ fidx)
{
  int b = blockIdx.x, t = threadIdx.x;       // t = h*16 + l*4 + p
  int l = (t >> 2) & 3;
  float off0 = off_buf[b * 256 + 2 * t]     + boff[2 * t];
  float off1 = off_buf[b * 256 + 2 * t + 1] + boff[2 * t + 1];
  int Hi = shapes[2 * l], Wi = shapes[2 * l + 1];
  float Hf = (float)Hi, Wf = (float)Wi;
  float r0 = refpts[b * 8 + 2 * l], r1 = refpts[b * 8 + 2 * l + 1];
  float l0 = fminf(fmaxf(r0 + off0 / Wf, 0.f), 0.999f);
  float l1 = fminf(fmaxf(r1 + off1 / Hf, 0.f), 0.999f);
  int i0 = (int)(l0 * Hf);
  int i1 = (int)(l1 * Wf);
  fidx[b * 128 + t] = i0 + i1 * Hi + lvlst[l];
}

// ---------------------------------------------------------------------------
// MFMA level-attention (unchanged from round 2)
// ---------------------------------------------------------------------------
__global__ __launch_bounds__(256) void k_attn_mfma(
    const ushort_t* __restrict__ qbf, const ushort_t* __restrict__ xbf,
    const float* __restrict__ Wattn, const int* __restrict__ fidx,
    float* __restrict__ attn)
{
  __shared__ __align__(16) unsigned Bs[256 * 34];   // [c'][j-pair] stride 34 words
  __shared__ __align__(16) ushort_t As[64 * 72];    // [u][j] stride 72 (144 B)
  __shared__ int fis[256];
  __shared__ float red[256 * 4];
  int h = blockIdx.z, l = blockIdx.y;
  int p = blockIdx.x >> 2, tg = blockIdx.x & 3;
  int t = threadIdx.x;
  int lane = t & 63, w = t >> 6;
  int quad = lane >> 4, l15 = lane & 15;
  int qcol = p * 4 + tg;
  fis[t] = fidx[(tg * 256 + t) * 128 + h * 16 + l * 4 + p];
  __syncthreads();
  f4 acc[4][4];
  #pragma unroll
  for (int mi = 0; mi < 4; ++mi)
    #pragma unroll
    for (int ni = 0; ni < 4; ++ni) acc[mi][ni] = (f4)0.f;

  for (int jt = 0; jt < 4; ++jt) {
    if (jt) __syncthreads();
    #pragma unroll 4
    for (int jq = 0; jq < 16; ++jq) {
      int j0 = jt * 64 + jq * 4;
      unsigned a0 = xbf[fis[j0 + 0] * 256 + t];
      unsigned a1 = xbf[fis[j0 + 1] * 256 + t];
      unsigned a2 = xbf[fis[j0 + 2] * 256 + t];
      unsigned a3 = xbf[fis[j0 + 3] * 256 + t];
      uint2 v; v.x = a0 | (a1 << 16); v.y = a2 | (a3 << 16);
      *(uint2*)&Bs[t * 34 + jq * 2] = v;
    }
    {
      int u = t >> 2, jj0 = (t & 3) * 16;
      const u4* src = (const u4*)(qbf + (u * 16 + qcol) * 256 + jt * 64 + jj0);
      u4 s0 = src[0], s1 = src[1];
      u4* dst = (u4*)(As + u * 72 + jj0);
      dst[0] = s0; dst[1] = s1;
    }
    __syncthreads();
    #pragma unroll
    for (int ks = 0; ks < 2; ++ks) {
      bh8 af[4], bfv[4];
      #pragma unroll
      for (int mi = 0; mi < 4; ++mi)
        af[mi] = *(bh8*)(As + (mi * 16 + l15) * 72 + ks * 32 + quad * 8);
      #pragma unroll
      for (int ni = 0; ni < 4; ++ni) {
        int n = w * 64 + ni * 16 + l15;
        const unsigned* bp = &Bs[n * 34 + ks * 16 + quad * 4];
        uint2 b0 = *(const uint2*)bp;
        uint2 b1 = *(const uint2*)(bp + 2);
        u4 bb; bb.x = b0.x; bb.y = b0.y; bb.z = b1.x; bb.w = b1.y;
        bfv[ni] = __builtin_bit_cast(bh8, bb);
      }
      #pragma unroll
      for (int mi = 0; mi < 4; ++mi)
        #pragma unroll
        for (int ni = 0; ni < 4; ++ni)
          acc[mi][ni] = __builtin_amdgcn_mfma_f32_16x16x32_bf16(af[mi], bfv[ni], acc[mi][ni], 0, 0, 0);
    }
  }
  const float* Wb = Wattn + (h * 4 + l) * 65536;
  #pragma unroll
  for (int a = 0; a < 4; ++a) {
    #pragma unroll
    for (int mi = 0; mi < 4; ++mi) {
      #pragma unroll
      for (int r = 0; r < 4; ++r) {
        int u = mi * 16 + quad * 4 + r;
        const float* wr = Wb + (a * 64 + u) * 256 + w * 64 + l15;
        float s = acc[mi][0][r] * wr[0]  + acc[mi][1][r] * wr[16]
                + acc[mi][2][r] * wr[32] + acc[mi][3][r] * wr[48];
        s += __shfl_xor(s, 1, 64); s += __shfl_xor(s, 2, 64);
        s += __shfl_xor(s, 4, 64); s += __shfl_xor(s, 8, 64);
        if (l15 == 0) red[(a * 64 + u) * 4 + w] = s;
      }
    }
  }
  __syncthreads();
  {
    int a = t >> 6, u = t & 63;
    float s = red[t * 4 + 0] + red[t * 4 + 1] + red[t * 4 + 2] + red[t * 4 + 3];
    attn[(h * 272 + l * 4 + a) * 1024 + u * 16 + qcol] = s;
  }
}

// ---------------------------------------------------------------------------
// bf16 MFMA GEMM core, abt form (unchanged)
// ---------------------------------------------------------------------------
template <typename OutT>
__device__ __forceinline__ void gemm_abt_core(
    const ushort_t* __restrict__ A, const ushort_t* __restrict__ B,
    OutT* __restrict__ C, int ldC, int m0, int n0)
{
  __shared__ __align__(16) ushort_t As[128 * 40];
  __shared__ __align__(16) ushort_t Bs[128 * 40];
  int t = threadIdx.x;
  int lane = t & 63, w = t >> 6;
  int quad = lane >> 4, l15 = lane & 15;
  int wm = w >> 1, wn = w & 1;
  f4 acc[4][4];
  #pragma unroll
  for (int mi = 0; mi < 4; ++mi)
    #pragma unroll
    for (int ni = 0; ni < 4; ++ni) acc[mi][ni] = (f4)0.f;
  int row = t >> 1, kh = (t & 1) * 16;
  for (int k0 = 0; k0 < 256; k0 += 32) {
    if (k0) __syncthreads();
    {
      const u4* ga = (const u4*)(A + (m0 + row) * 256 + k0 + kh);
      u4 v0 = ga[0], v1 = ga[1];
      u4* da = (u4*)(As + row * 40 + kh); da[0] = v0; da[1] = v1;
      const u4* gb = (const u4*)(B + (n0 + row) * 256 + k0 + kh);
      u4 u0 = gb[0], u1 = gb[1];
      u4* db = (u4*)(Bs + row * 40 + kh); db[0] = u0; db[1] = u1;
    }
    __syncthreads();
    bh8 af[4], bfv[4];
    #pragma unroll
    for (int mi = 0; mi < 4; ++mi)
      af[mi] = *(bh8*)(As + (wm * 64 + mi * 16 + l15) * 40 + quad * 8);
    #pragma unroll
    for (int ni = 0; ni < 4; ++ni)
      bfv[ni] = *(bh8*)(Bs + (wn * 64 + ni * 16 + l15) * 40 + quad * 8);
    #pragma unroll
    for (int mi = 0; mi < 4; ++mi)
      #pragma unroll
      for (int ni = 0; ni < 4; ++ni)
        acc[mi][ni] = __builtin_amdgcn_mfma_f32_16x16x32_bf16(af[mi], bfv[ni], acc[mi][ni], 0, 0, 0);
  }
  #pragma unroll
  for (int mi = 0; mi < 4; ++mi)
    #pragma unroll
    for (int ni = 0; ni < 4; ++ni)
      #pragma unroll
      for (int r = 0; r < 4; ++r) {
        int mg = m0 + wm * 64 + mi * 16 + quad * 4 + r;
        int ng = n0 + wn * 64 + ni * 16 + l15;
        if constexpr (sizeof(OutT) == 4) C[mg * ldC + ng] = acc[mi][ni][r];
        else C[mg * ldC + ng] = (OutT)f2bf(acc[mi][ni][r]);
      }
}

__global__ __launch_bounds__(256) void gemm4_k(
    const ushort_t* __restrict__ addk, const ushort_t* __restrict__ Wattn4,
    ushort_t* __restrict__ tmp)
{
  int h = blockIdx.z;
  gemm_abt_core<ushort_t>(addk, Wattn4 + h * 65536, tmp + h * 65536,
                          256, blockIdx.y * 128, blockIdx.x * 128);
}
__global__ __launch_bounds__(256) void gemm5_k(
    const ushort_t* __restrict__ tmp, const ushort_t* __restrict__ qbf,
    float* __restrict__ attn)
{
  int h = blockIdx.z;
  gemm_abt_core<float>(tmp + h * 65536, qbf, attn + h * 278528 + 16384,
                       1024, blockIdx.y * 128, blockIdx.x * 128);
}
__global__ __launch_bounds__(256) void gemm_val_k(
    const ushort_t* __restrict__ kbar, const ushort_t* __restrict__ abar,
    const ushort_t* __restrict__ Wval, float* __restrict__ Y1, float* __restrict__ Y2)
{
  int z = blockIdx.z, h = z & 7;
  const ushort_t* A = (z < 8 ? kbar : abar) + h * 262144;
  const ushort_t* B = Wval + (z < 8 ? 2 * h : 2 * h + 1) * 65536;
  float* C = (z < 8 ? Y1 : Y2) + h * 262144;
  gemm_abt_core<float>(A, B, C, 256, blockIdx.y * 128, blockIdx.x * 128);
}

// ---------------------------------------------------------------------------
// TN GEMM (unchanged)
// ---------------------------------------------------------------------------
__global__ __launch_bounds__(256) void gemm_tn_k(
    const ushort_t* __restrict__ attn2, const ushort_t* __restrict__ addk,
    ushort_t* __restrict__ abar)
{
  __shared__ __align__(16) unsigned Asu[128 * 20];
  __shared__ __align__(16) unsigned Bsu[128 * 20];
  int h = blockIdx.z;
  const ushort_t* A = attn2 + h * 262144;
  const ushort_t* B = addk;
  ushort_t* C = abar + h * 262144;
  int m0 = blockIdx.y * 128, n0 = blockIdx.x * 128;
  int t = threadIdx.x;
  int lane = t & 63, w = t >> 6;
  int quad = lane >> 4, l15 = lane & 15;
  int wm = w >> 1, wn = w & 1;
  f4 acc[4][4];
  #pragma unroll
  for (int mi = 0; mi < 4; ++mi)
    #pragma unroll
    for (int ni = 0; ni < 4; ++ni) acc[mi][ni] = (f4)0.f;
  int col = t & 127, half = t >> 7;
  for (int k0 = 0; k0 < 256; k0 += 32) {
    if (k0) __syncthreads();
    #pragma unroll
    for (int i = 0; i < 4; ++i) {
      int kpp = half * 4 + i;
      int kk = k0 + kpp * 4;
      unsigned x0 = A[(kk + 0) * 1024 + m0 + col];
      unsigned x1 = A[(kk + 1) * 1024 + m0 + col];
      unsigned x2 = A[(kk + 2) * 1024 + m0 + col];
      unsigned x3 = A[(kk + 3) * 1024 + m0 + col];
      uint2 va; va.x = x0 | (x1 << 16); va.y = x2 | (x3 << 16);
      *(uint2*)&Asu[col * 20 + kpp * 2] = va;
      unsigned y0 = B[(kk + 0) * 256 + n0 + col];
      unsigned y1 = B[(kk + 1) * 256 + n0 + col];
      unsigned y2 = B[(kk + 2) * 256 + n0 + col];
      unsigned y3 = B[(kk + 3) * 256 + n0 + col];
      uint2 vb; vb.x = y0 | (y1 << 16); vb.y = y2 | (y3 << 16);
      *(uint2*)&Bsu[col * 20 + kpp * 2] = vb;
    }
    __syncthreads();
    bh8 af[4], bfv[4];
    #pragma unroll
    for (int mi = 0; mi < 4; ++mi)
      af[mi] = *(bh8*)((const ushort_t*)Asu + (wm * 64 + mi * 16 + l15) * 40 + quad * 8);
    #pragma unroll
    for (int ni = 0; ni < 4; ++ni)
      bfv[ni] = *(bh8*)((const ushort_t*)Bsu + (wn * 64 + ni * 16 + l15) * 40 + quad * 8);
    #pragma unroll
    for (int mi = 0; mi < 4; ++mi)
      #pragma unroll
      for (int ni = 0; ni < 4; ++ni)
        acc[mi][ni] = __builtin_amdgcn_mfma_f32_16x16x32_bf16(af[mi], bfv[ni], acc[mi][ni], 0, 0, 0);
  }
  #pragma unroll
  for (int mi = 0; mi < 4; ++mi)
    #pragma unroll
    for (int ni = 0; ni < 4; ++ni)
      #pragma unroll
      for (int r = 0; r < 4; ++r) {
        int mg = m0 + wm * 64 + mi * 16 + quad * 4 + r;
        int ng = n0 + wn * 64 + ni * 16 + l15;
        C[mg * 256 + ng] = f2bf(acc[mi][ni][r]);
      }
}

// ---------------------------------------------------------------------------
// softmax: 256 blocks x 256 thr; thread = (row-group rg of 34 rows, col ci)
// single global read pass, values in registers, LDS cross-group reduce.
// fp32 written only for rows<16 (k_kbar input); bf16 for rows>=16 (gemm_tn).
// ---------------------------------------------------------------------------
__global__ __launch_bounds__(256) void k_softmax(
    float* __restrict__ attn, ushort_t* __restrict__ attn2bf,
    float* __restrict__ s1, float* __restrict__ s2)
{
  __shared__ float red[8][32];
  int h = blockIdx.y;
  int b = blockIdx.x * 32 + (threadIdx.x & 31);
  int rg = threadIdx.x >> 5;
  const int R0 = rg * 34;
  float* col = attn + h * 278528 + b;
  float v[34];
  float m = -1e30f;
  #pragma unroll
  for (int i = 0; i < 34; ++i) {
    v[i] = col[(R0 + i) * 1024];
    m = fmaxf(m, v[i]);
  }
  red[rg][threadIdx.x & 31] = m;
  __syncthreads();
  #pragma unroll
  for (int j = 0; j < 8; ++j) m = fmaxf(m, red[j][threadIdx.x & 31]);
  float sum = 0.f;
  #pragma unroll
  for (int i = 0; i < 34; ++i) { v[i] = expf(v[i] - m); sum += v[i]; }
  __syncthreads();
  red[rg][threadIdx.x & 31] = sum;
  __syncthreads();
  float tot = 0.f;
  #pragma unroll
  for (int j = 0; j < 8; ++j) tot += red[j][threadIdx.x & 31];
  float inv = 1.f / tot;
  #pragma unroll
  for (int i = 0; i < 34; ++i) {
    int r = R0 + i;
    float x = v[i] * inv;
    if (r < 16) col[r * 1024] = x;
    else attn2bf[h * 262144 + (r - 16) * 1024 + b] = f2bf(x);
  }
  if (rg == 0) {
    float sa = 0.f;
    #pragma unroll
    for (int i = 0; i < 16; ++i) sa += v[i];
    float sn = sa * inv;
    s1[h * 1024 + b] = sn;
    s2[h * 1024 + b] = 1.f - sn;
  }
}

// --------------- kbar[h][b] = sum_{r<16} attn[h][r][b] * key_{h,r,b} --------
__global__ __launch_bounds__(256) void k_kbar(
    const ushort_t* __restrict__ xbf, const float* __restrict__ attn,
    const int* __restrict__ fidx, ushort_t* __restrict__ kbar)
{
  __shared__ float aw[256];     // [r][bi]
  __shared__ int fis2[256];     // [bi][r]
  int h = blockIdx.y, b0 = blockIdx.x * 16;
  int t = threadIdx.x;
  aw[t] = attn[(h * 272 + (t >> 4)) * 1024 + b0 + (t & 15)];
  fis2[t] = fidx[(b0 + (t >> 4)) * 128 + h * 16 + (t & 15)];
  __syncthreads();
  #pragma unroll 2
  for (int bi = 0; bi < 16; ++bi) {
    float s = 0.f;
    #pragma unroll
    for (int r = 0; r < 16; ++r)
      s += aw[r * 16 + bi] * bf2f(xbf[fis2[bi * 16 + r] * 256 + t]);
    kbar[(h * 1024 + b0 + bi) * 256 + t] = f2bf(s);
  }
}

// ------------------------------- final combine ------------------------------
__global__ __launch_bounds__(256) void k_combine(
    const float* __restrict__ q, const float* __restrict__ Wmix,
    const float* __restrict__ Y1, const float* __restrict__ Y2,
    const float* __restrict__ s1, const float* __restrict__ s2,
    const float* __restrict__ bval, float* __restrict__ out)
{
  int b = blockIdx.x, c = threadIdx.x;
  float w[9];
  float m = -1e30f;
  #pragma unroll
  for (int j = 0; j < 9; ++j) { w[j] = Wmix[c * 9 + j]; m = fmaxf(m, w[j]); }
  float tot = 0.f;
  #pragma unroll
  for (int j = 0; j < 9; ++j) { w[j] = expf(w[j] - m); tot += w[j]; }
  float inv = 1.f / tot;
  float res = q[b * 256 + c] * w[8] * inv;
  #pragma unroll
  for (int hh = 0; hh < 8; ++hh) {
    float y = Y1[(hh * 1024 + b) * 256 + c] + Y2[(hh * 1024 + b) * 256 + c]
            + s1[hh * 1024 + b] * bval[(2 * hh) * 256 + c]
            + s2[hh * 1024 + b] * bval[(2 * hh + 1) * 256 + c];
    res += w[hh] * inv * y;
  }
  out[b * 256 + c] = res;
}

extern "C" void kernel_launch(void* const* d_in, const int* in_sizes, int n_in,
                              void* d_out, int out_size, void* d_ws, size_t ws_size,
                              hipStream_t stream) {
  (void)in_sizes; (void)n_in; (void)out_size; (void)ws_size;
  const float* q      = (const float*)d_in[0];
  const float* refpts = (const float*)d_in[1];
  const float* xin    = (const float*)d_in[2];
  const int*   shapes = (const int*)d_in[3];
  const float* addk   = (const float*)d_in[4];
  const int*   lvlst  = (const int*)d_in[5];
  const float* Woff   = (const float*)d_in[6];
  const float* boff   = (const float*)d_in[7];
  const float* Wattn  = (const float*)d_in[8];
  const float* Wval   = (const float*)d_in[9];
  const float* bval   = (const float*)d_in[10];
  const float* Wmix   = (const float*)d_in[11];
  float* out = (float*)d_out;
  float* ws  = (float*)d_ws;

  int*   fidx    = (int*)ws;                  // [0, 131072)
  float* off_buf = ws + 131072;               // 262144 f
  float* s1      = ws + 393216;               // 8192
  float* s2      = ws + 401408;               // 8192
  float* attn    = ws + 409600;               // 8*272*1024 fp32 (dead after k_kbar)
  float* Y1      = ws + 409600;               // overlaps attn (written by gemm_val_k)
  float* Y2      = ws + 2506752;               // 8*1024*256
  ushort_t* arena = (ushort_t*)(ws + 4603904);
  ushort_t* q_bf     = arena;                 // 262144
  ushort_t* xin_bf   = arena + 262144;        // 3403264
  ushort_t* addk_bf  = arena + 3665408;       // 65536
  ushort_t* Wval_bf  = arena + 3730944;       // 1048576
  ushort_t* Wattn4_bf= arena + 4779520;       // 524288
  ushort_t* tmp_bf   = arena + 5303808;       // 524288
  ushort_t* attn2_bf = arena + 5828096;       // 2097152
  ushort_t* kbar_bf  = arena + 7925248;       // 2097152
  ushort_t* abar_bf  = arena + 10022400;      // 2097152

  k_cast<<<2048, 256, 0, stream>>>(q, xin, addk, Wval, Wattn, arena);
  gemm_f32<<<dim3(4, 16, 1), 256, 0, stream>>>(q, Woff, off_buf, 1024, 256, 256, 256);
  k_indices<<<1024, 128, 0, stream>>>(off_buf, boff, refpts, shapes, lvlst, fidx);
  k_attn_mfma<<<dim3(16, 4, 8), 256, 0, stream>>>(q_bf, xin_bf, Wattn, fidx, attn);
  gemm4_k<<<dim3(2, 2, 8), 256, 0, stream>>>(addk_bf, Wattn4_bf, tmp_bf);
  gemm5_k<<<dim3(8, 2, 8), 256, 0, stream>>>(tmp_bf, q_bf, attn);
  k_softmax<<<dim3(32, 8), 256, 0, stream>>>(attn, attn2_bf, s1, s2);
  k_kbar<<<dim3(64, 8), 256, 0, stream>>>(xin_bf, attn, fidx, kbar_bf);
  gemm_tn_k<<<dim3(2, 8, 8), 256, 0, stream>>>(attn2_bf, addk_bf, abar_bf);
  gemm_val_k<<<dim3(2, 8, 16), 256, 0, stream>>>(kbar_bf, abar_bf, Wval_bf, Y1, Y2);
  k_combine<<<1024, 256, 0, stream>>>(q, Wmix, Y1, Y2, s1, s2, bval, out);
}